// Round 4
// baseline (361.557 us; speedup 1.0000x reference)
//
#include <hip/hip_runtime.h>
#include <hip/hip_bf16.h>
#include <math.h>

// AdaptiveContrastiveLoss: x[4096][512] f32 -> scalar f32.
// R3: both 64MB scan kernels (hist_pass, compact_loss) were MLP=1
// (VGPR=12, one load in flight, VALUBusy 5%, 0.42 TB/s). Restructured to
// fixed 8-iteration unrolled loops with all 8 float4 loads issued up front.
// ws layout: sim 64MB | xnb 4MB | posCand 1MB | negCand 1MB | Meta (~33KB).

#define N 4096
#define D 512
#define NN 16777216u
#define NB 8192          // uniform value bins
#define CAND_CAP 262144  // per-side global candidate capacity (1MB)
#define LCAP 2048        // per-block LDS candidate capacity
#define SCAN_BLOCKS 2048
#define SCAN_ITERS 8     // NN/4 / (SCAN_BLOCKS*256) == 8 exactly

typedef __attribute__((ext_vector_type(8))) short bf16x8;
typedef __attribute__((ext_vector_type(4))) float f32x4;

struct Meta {
  unsigned int hist[NB];
  unsigned int bp, rwp;      // pos threshold bin + rank within bin
  unsigned int bn_, rwn;     // neg threshold bin + rank within bin
  unsigned int pcCnt, ncCnt; // candidate counts
  unsigned int pcnt, ncnt;   // strict mask counts (accumulated)
  double psum, nsum;         // strict mask numerators
};

// monotone value->bin (identical instruction in every kernel: single fmaf)
__device__ __forceinline__ int val2bin(float s) {
  int b = (int)fmaf(s, 4096.0f, 4096.0f);  // floor((s+1)*4096) for s>=-1
  return b < 0 ? 0 : (b > NB - 1 ? NB - 1 : b);
}
// monotone float<->sortable-uint (no NaNs in this data)
__device__ __forceinline__ unsigned int f2key(float f) {
  unsigned int u = __float_as_uint(f);
  return (u & 0x80000000u) ? ~u : (u | 0x80000000u);
}
__device__ __forceinline__ float key2f(unsigned int k) {
  unsigned int u = (k & 0x80000000u) ? (k ^ 0x80000000u) : ~k;
  return __uint_as_float(u);
}
__device__ __forceinline__ unsigned short f2bf(float f) {  // RNE, matches __float2bfloat16
  unsigned int u = __float_as_uint(f);
  u += 0x7FFFu + ((u >> 16) & 1u);
  return (unsigned short)(u >> 16);
}

// ---- 1) row norms + normalize + f32->bf16 convert. one block per row ----
__global__ __launch_bounds__(256) void norm_conv(const float* __restrict__ x,
                                                 unsigned short* __restrict__ xnb) {
  const int row = blockIdx.x;
  const int tid = threadIdx.x;  // 256 threads x 2 floats
  const float2 v = ((const float2*)(x + (size_t)row * D))[tid];
  float s = v.x * v.x + v.y * v.y;
#pragma unroll
  for (int o = 32; o > 0; o >>= 1) s += __shfl_xor(s, o);
  __shared__ float wsum[4];
  __shared__ float s_rinv;
  if ((tid & 63) == 0) wsum[tid >> 6] = s;
  __syncthreads();
  if (tid == 0) {
    float t = wsum[0] + wsum[1] + wsum[2] + wsum[3];
    s_rinv = 1.0f / fmaxf(sqrtf(t), 1e-8f);
  }
  __syncthreads();
  const float r = s_rinv;
  unsigned short lo = f2bf(v.x * r), hi = f2bf(v.y * r);
  ((ushort2*)(xnb + (size_t)row * D))[tid] = make_ushort2(lo, hi);
}

// ---- 2) bf16 MFMA GEMM: sim = Xnb * Xnb^T, 128x128 tile, 4 waves ----
#define BM 128
#define BK 64
#define LDK 72  // padded row stride (144B = 16*9: 16B-aligned, 2-way-bank free)
__global__ __launch_bounds__(256) void gemm_sim(const unsigned short* __restrict__ xnb,
                                                float* __restrict__ sim) {
  __shared__ unsigned short As[BM][LDK];
  __shared__ unsigned short Bs[BM][LDK];
  const int tid = threadIdx.x;
  const int bm = blockIdx.x * BM;
  const int bn = blockIdx.y * BM;
  const int w = tid >> 6, l = tid & 63;
  const int wr = w >> 1, wc = w & 1;
  const int lr = l & 15, lk = (l >> 4) * 8;

  const int srow = tid >> 3;        // 0..31
  const int skoff = (tid & 7) * 8;  // 0..56

  f32x4 acc[4][4] = {};

  for (int kt = 0; kt < D; kt += BK) {
    bf16x8 av[4], bv[4];
#pragma unroll
    for (int r4 = 0; r4 < 4; ++r4) {
      const int row = srow + r4 * 32;
      av[r4] = *(const bf16x8*)&xnb[(size_t)(bm + row) * D + kt + skoff];
      bv[r4] = *(const bf16x8*)&xnb[(size_t)(bn + row) * D + kt + skoff];
    }
    __syncthreads();  // previous tile's compute done
#pragma unroll
    for (int r4 = 0; r4 < 4; ++r4) {
      const int row = srow + r4 * 32;
      *(bf16x8*)&As[row][skoff] = av[r4];
      *(bf16x8*)&Bs[row][skoff] = bv[r4];
    }
    __syncthreads();
#pragma unroll
    for (int kk = 0; kk < BK; kk += 32) {
      bf16x8 af[4], bf[4];
#pragma unroll
      for (int m = 0; m < 4; ++m)
        af[m] = *(const bf16x8*)&As[wr * 64 + m * 16 + lr][kk + lk];
#pragma unroll
      for (int n = 0; n < 4; ++n)
        bf[n] = *(const bf16x8*)&Bs[wc * 64 + n * 16 + lr][kk + lk];
#pragma unroll
      for (int m = 0; m < 4; ++m)
#pragma unroll
        for (int n = 0; n < 4; ++n)
          acc[m][n] = __builtin_amdgcn_mfma_f32_16x16x32_bf16(af[m], bf[n], acc[m][n], 0, 0, 0);
    }
  }
  // C/D layout: col = lane&15, row = (lane>>4)*4 + e  [measured m89/m91]
  const int orow = bm + wr * 64 + (l >> 4) * 4;
  const int ocol = bn + wc * 64 + lr;
#pragma unroll
  for (int m = 0; m < 4; ++m)
#pragma unroll
    for (int n = 0; n < 4; ++n)
#pragma unroll
      for (int e = 0; e < 4; ++e)
        sim[(size_t)(orow + m * 16 + e) * N + ocol + n * 16] = acc[m][n][e];
}

// ---- 3) uniform 8192-bin histogram; 8 loads in flight per wave ----
__global__ __launch_bounds__(256) void hist_pass(const float* __restrict__ sim,
                                                 Meta* __restrict__ m) {
  __shared__ unsigned int h[NB];
  const int tid = threadIdx.x;
  for (int i = tid; i < NB; i += 256) h[i] = 0;
  __syncthreads();
  const float4* s4 = (const float4*)sim;
  const unsigned int base = blockIdx.x * 256u + tid;
  float4 v[SCAN_ITERS];
#pragma unroll
  for (int k = 0; k < SCAN_ITERS; ++k)
    v[k] = s4[(size_t)base + (size_t)k * (SCAN_BLOCKS * 256u)];
#pragma unroll
  for (int k = 0; k < SCAN_ITERS; ++k) {
    atomicAdd(&h[val2bin(v[k].x)], 1u);
    atomicAdd(&h[val2bin(v[k].y)], 1u);
    atomicAdd(&h[val2bin(v[k].z)], 1u);
    atomicAdd(&h[val2bin(v[k].w)], 1u);
  }
  __syncthreads();
  for (int i = tid; i < NB; i += 256) {
    const unsigned int c = h[i];
    if (c) atomicAdd(&m->hist[i], c);
  }
}

// ---- 4) find the two threshold bins + ranks within ----
__global__ __launch_bounds__(256) void scan_bins(Meta* __restrict__ m,
                                                 unsigned int kneg, unsigned int kpos) {
  __shared__ unsigned int part[256];
  const int tid = threadIdx.x;
  unsigned int s = 0;
  for (int i = 0; i < NB / 256; ++i) s += m->hist[tid * (NB / 256) + i];
  part[tid] = s;
  __syncthreads();
  if (tid == 0) {
    const unsigned int targets[2] = {kpos, kneg};
    unsigned int outb[2], outr[2];
    for (int t = 0; t < 2; ++t) {
      unsigned int r = targets[t], cum = 0, seg = 0;
      while (seg < 255 && cum + part[seg] <= r) { cum += part[seg]; seg++; }
      unsigned int b = seg * (NB / 256);
      while (b < NB - 1 && cum + m->hist[b] <= r) { cum += m->hist[b]; b++; }
      outb[t] = b;
      outr[t] = r - cum;
    }
    m->bp = outb[0]; m->rwp = outr[0];
    m->bn_ = outb[1]; m->rwn = outr[1];
  }
}

// ---- 5) fused strict-loss + LDS candidate compact; 8 loads in flight ----
__global__ __launch_bounds__(256) void compact_loss(const float* __restrict__ sim,
                                                    Meta* __restrict__ m,
                                                    float* __restrict__ pcand,
                                                    float* __restrict__ ncand) {
  __shared__ float lp[LCAP], ln[LCAP];
  __shared__ unsigned int lpc, lnc, pbase, nbase;
  const int tid = threadIdx.x;
  if (tid == 0) { lpc = 0; lnc = 0; }
  __syncthreads();
  const unsigned int bp = m->bp, bn = m->bn_;
  const float4* s4 = (const float4*)sim;
  const unsigned int base = blockIdx.x * 256u + tid;
  float4 v[SCAN_ITERS];
#pragma unroll
  for (int k = 0; k < SCAN_ITERS; ++k)
    v[k] = s4[(size_t)base + (size_t)k * (SCAN_BLOCKS * 256u)];

  float ps = 0.f, ns = 0.f;
  unsigned int pc = 0, nc = 0;
#pragma unroll
  for (int k = 0; k < SCAN_ITERS; ++k) {
    const float f[4] = {v[k].x, v[k].y, v[k].z, v[k].w};
#pragma unroll
    for (int e = 0; e < 4; ++e) {
      const float s = f[e];
      const unsigned int b = (unsigned int)val2bin(s);
      if (b > bp) { pc++; ps += fmaxf(1.0f - s, 0.0f); }
      else if (b == bp) { const unsigned int idx = atomicAdd(&lpc, 1u); if (idx < LCAP) lp[idx] = s; }
      if (b < bn) { nc++; ns += fmaxf(s, 0.0f); }
      else if (b == bn) { const unsigned int idx = atomicAdd(&lnc, 1u); if (idx < LCAP) ln[idx] = s; }
    }
  }
  double psd = ps, nsd = ns;
#pragma unroll
  for (int o = 32; o > 0; o >>= 1) {
    psd += __shfl_xor(psd, o);
    nsd += __shfl_xor(nsd, o);
    pc += __shfl_xor(pc, o);
    nc += __shfl_xor(nc, o);
  }
  __shared__ double sps[4], sns[4];
  __shared__ unsigned int spc[4], snc[4];
  if ((tid & 63) == 0) { const int w = tid >> 6; sps[w] = psd; sns[w] = nsd; spc[w] = pc; snc[w] = nc; }
  __syncthreads();
  if (tid == 0) {
    atomicAdd(&m->psum, sps[0] + sps[1] + sps[2] + sps[3]);
    atomicAdd(&m->nsum, sns[0] + sns[1] + sns[2] + sns[3]);
    atomicAdd(&m->pcnt, spc[0] + spc[1] + spc[2] + spc[3]);
    atomicAdd(&m->ncnt, snc[0] + snc[1] + snc[2] + snc[3]);
    // one global atomic per block per side
    pbase = atomicAdd(&m->pcCnt, lpc < LCAP ? lpc : LCAP);
    nbase = atomicAdd(&m->ncCnt, lnc < LCAP ? lnc : LCAP);
  }
  __syncthreads();
  const unsigned int npf = lpc < LCAP ? lpc : LCAP;
  const unsigned int nnf = lnc < LCAP ? lnc : LCAP;
  for (unsigned int i = tid; i < npf; i += 256) {
    const unsigned int gi = pbase + i;
    if (gi < CAND_CAP) pcand[gi] = lp[i];
  }
  for (unsigned int i = tid; i < nnf; i += 256) {
    const unsigned int gi = nbase + i;
    if (gi < CAND_CAP) ncand[gi] = ln[i];
  }
}

// ---- 6) exact select on candidates (key-space narrowing) + finalize ----
#define SF_T 1024
__global__ __launch_bounds__(SF_T) void select_finalize(Meta* __restrict__ m,
                                                        const float* __restrict__ pcand,
                                                        const float* __restrict__ ncand,
                                                        float* __restrict__ out) {
  __shared__ unsigned int h[1024];
  __shared__ unsigned int s_lo, s_hi, s_r;
  __shared__ unsigned int rmin[16], rmax[16], rcnt[16];
  __shared__ double racc[16];
  const int tid = threadIdx.x;
  const int lane = tid & 63, wid = tid >> 6;

  for (int side = 0; side < 2; ++side) {
    const unsigned int rawCnt = side ? m->ncCnt : m->pcCnt;
    const unsigned int cnt = rawCnt < CAND_CAP ? rawCnt : CAND_CAP;
    const float* cand = side ? ncand : pcand;
    if (tid == 0) s_r = side ? m->rwn : m->rwp;

    // key min/max over candidates
    unsigned int kmin = 0xFFFFFFFFu, kmax = 0u;
    for (unsigned int i = tid; i < cnt; i += SF_T) {
      const unsigned int k = f2key(cand[i]);
      kmin = min(kmin, k); kmax = max(kmax, k);
    }
#pragma unroll
    for (int o = 32; o > 0; o >>= 1) {
      kmin = min(kmin, (unsigned int)__shfl_xor((int)kmin, o));
      kmax = max(kmax, (unsigned int)__shfl_xor((int)kmax, o));
    }
    if (lane == 0) { rmin[wid] = kmin; rmax[wid] = kmax; }
    __syncthreads();
    if (tid == 0) {
      unsigned int lo = 0xFFFFFFFFu, hi = 0u;
      for (int i = 0; i < SF_T / 64; ++i) { lo = min(lo, rmin[i]); hi = max(hi, rmax[i]); }
      s_lo = lo; s_hi = hi + 1u;
    }

    // narrow [lo,hi) by 1024-way histogram until single key
    for (;;) {
      __syncthreads();
      const unsigned int lo = s_lo, hi = s_hi;
      if (hi - lo <= 1u) break;
      const unsigned int span = hi - lo;
      unsigned int shift = 0;
      while (((span - 1u) >> shift) > 1023u) shift++;
      for (int i = tid; i < 1024; i += SF_T) h[i] = 0;
      __syncthreads();
      for (unsigned int i = tid; i < cnt; i += SF_T) {
        const unsigned int k = f2key(cand[i]);
        if (k >= lo && k < hi) atomicAdd(&h[(k - lo) >> shift], 1u);
      }
      __syncthreads();
      if (tid == 0) {
        unsigned int r = s_r, cum = 0, d = 0;
        for (; d < 1024; ++d) { const unsigned int c = h[d]; if (cum + c > r) break; cum += c; }
        if (d == 1024) d = 1023;
        s_r = r - cum;
        const unsigned int nlo = lo + (d << shift);
        unsigned int nhi = nlo + (1u << shift);
        if (nhi > hi || nhi < nlo) nhi = hi;
        s_lo = nlo; s_hi = nhi;
      }
    }
    __syncthreads();
    const float T = key2f(s_lo);

    // strict boundary contributions
    float accf = 0.f;
    unsigned int c2 = 0;
    for (unsigned int i = tid; i < cnt; i += SF_T) {
      const float s = cand[i];
      if (side == 0) { if (s > T) { c2++; accf += fmaxf(1.0f - s, 0.0f); } }
      else           { if (s < T) { c2++; accf += fmaxf(s, 0.0f); } }
    }
    double accd = accf;
#pragma unroll
    for (int o = 32; o > 0; o >>= 1) { accd += __shfl_xor(accd, o); c2 += __shfl_xor(c2, o); }
    if (lane == 0) { racc[wid] = accd; rcnt[wid] = c2; }
    __syncthreads();
    if (tid == 0) {
      double a = 0.0;
      unsigned int c = 0;
      for (int i = 0; i < SF_T / 64; ++i) { a += racc[i]; c += rcnt[i]; }
      if (side == 0) { m->psum += a; m->pcnt += c; }
      else           { m->nsum += a; m->ncnt += c; }
    }
    __syncthreads();
  }
  if (tid == 0)
    out[0] = (float)(m->psum / (double)m->pcnt + m->nsum / (double)m->ncnt);
}

extern "C" void kernel_launch(void* const* d_in, const int* in_sizes, int n_in,
                              void* d_out, int out_size, void* d_ws, size_t ws_size,
                              hipStream_t stream) {
  const float* x = (const float*)d_in[0];
  float* out = (float*)d_out;
  char* ws = (char*)d_ws;

  float* sim = (float*)ws;                                        // 64 MB
  unsigned short* xnb = (unsigned short*)(ws + (size_t)NN * 4);   // 4 MB
  float* pcand = (float*)(ws + (size_t)NN * 4 + (size_t)N * D * 2);          // 1 MB
  float* ncand = (float*)(ws + (size_t)NN * 4 + (size_t)N * D * 2 + CAND_CAP * 4);
  Meta* meta = (Meta*)(ws + (size_t)NN * 4 + (size_t)N * D * 2 + 2 * CAND_CAP * 4);

  const unsigned int kneg = (unsigned int)ceil((double)NN * 0.2);          // 3355444
  const unsigned int kpos = (unsigned int)ceil((double)NN * (1.0 - 0.2));  // 13421773

  hipMemsetAsync(meta, 0, sizeof(Meta), stream);
  norm_conv<<<N, 256, 0, stream>>>(x, xnb);
  dim3 ggrid(N / BM, N / BM);
  gemm_sim<<<ggrid, 256, 0, stream>>>(xnb, sim);
  hist_pass<<<SCAN_BLOCKS, 256, 0, stream>>>(sim, meta);
  scan_bins<<<1, 256, 0, stream>>>(meta, kneg, kpos);
  compact_loss<<<SCAN_BLOCKS, 256, 0, stream>>>(sim, meta, pcand, ncand);
  select_finalize<<<1, SF_T, 0, stream>>>(meta, pcand, ncand, out);
}

// Round 5
// 296.006 us; speedup vs baseline: 1.2215x; 1.2215x over previous
//
#include <hip/hip_runtime.h>
#include <hip/hip_bf16.h>
#include <math.h>

// AdaptiveContrastiveLoss: x[4096][512] f32 -> scalar f32.
// R4: eliminated the 64MB sim array entirely. Both full-matrix passes
// (histogram, loss) fused into GEMM epilogues; GEMM computed twice
// (17.2 GFLOP each) instead of streaming 192MB through an unexplained
// 0.42 TB/s scan floor. ws: xnb 4MB | pcand 1MB | ncand 1MB | Meta ~16.5KB.

#define N 4096
#define D 512
#define NN 16777216u
#define NB 4096          // uniform value bins
#define CAND_CAP 262144  // per-side global candidate capacity (1MB)
#define LCAP 1024        // per-block LDS candidate capacity (expect ~50/block)

typedef __attribute__((ext_vector_type(8))) short bf16x8;
typedef __attribute__((ext_vector_type(4))) float f32x4;

struct Meta {
  unsigned int hist[NB];
  unsigned int bp, rwp;      // pos threshold bin + rank within bin
  unsigned int bn_, rwn;     // neg threshold bin + rank within bin
  unsigned int pcCnt, ncCnt; // candidate counts
  unsigned int pcnt, ncnt;   // strict mask counts
  double psum, nsum;         // strict mask numerators
};

// monotone value->bin: floor((s+1)*2048), clamped. identical math everywhere.
__device__ __forceinline__ int val2bin(float s) {
  int b = (int)fmaf(s, 2048.0f, 2048.0f);
  return b < 0 ? 0 : (b > NB - 1 ? NB - 1 : b);
}
__device__ __forceinline__ unsigned int f2key(float f) {
  unsigned int u = __float_as_uint(f);
  return (u & 0x80000000u) ? ~u : (u | 0x80000000u);
}
__device__ __forceinline__ float key2f(unsigned int k) {
  unsigned int u = (k & 0x80000000u) ? (k ^ 0x80000000u) : ~k;
  return __uint_as_float(u);
}
__device__ __forceinline__ unsigned short f2bf(float f) {  // RNE
  unsigned int u = __float_as_uint(f);
  u += 0x7FFFu + ((u >> 16) & 1u);
  return (unsigned short)(u >> 16);
}

// ---- 1) row norms + normalize + f32->bf16 convert ----
__global__ __launch_bounds__(256) void norm_conv(const float* __restrict__ x,
                                                 unsigned short* __restrict__ xnb) {
  const int row = blockIdx.x;
  const int tid = threadIdx.x;
  const float2 v = ((const float2*)(x + (size_t)row * D))[tid];
  float s = v.x * v.x + v.y * v.y;
#pragma unroll
  for (int o = 32; o > 0; o >>= 1) s += __shfl_xor(s, o);
  __shared__ float wsum[4];
  __shared__ float s_rinv;
  if ((tid & 63) == 0) wsum[tid >> 6] = s;
  __syncthreads();
  if (tid == 0) {
    float t = wsum[0] + wsum[1] + wsum[2] + wsum[3];
    s_rinv = 1.0f / fmaxf(sqrtf(t), 1e-8f);
  }
  __syncthreads();
  const float r = s_rinv;
  ((ushort2*)(xnb + (size_t)row * D))[tid] = make_ushort2(f2bf(v.x * r), f2bf(v.y * r));
}

// ---- shared GEMM tile core: 128x128 tile, 4 waves, acc[4][4] f32x4/lane ----
#define BM 128
#define BK 64
#define LDK 72  // padded row stride (144B: 16B-aligned, 2-way-bank free)
__device__ __forceinline__ void compute_tile(const unsigned short* __restrict__ xnb,
                                             unsigned short As[BM][LDK],
                                             unsigned short Bs[BM][LDK],
                                             int bm, int bn, int tid,
                                             f32x4 acc[4][4]) {
  const int w = tid >> 6, l = tid & 63;
  const int wr = w >> 1, wc = w & 1;
  const int lr = l & 15, lk = (l >> 4) * 8;
  const int srow = tid >> 3;        // 0..31
  const int skoff = (tid & 7) * 8;  // 0..56

  for (int kt = 0; kt < D; kt += BK) {
    bf16x8 av[4], bv[4];
#pragma unroll
    for (int r4 = 0; r4 < 4; ++r4) {
      const int row = srow + r4 * 32;
      av[r4] = *(const bf16x8*)&xnb[(size_t)(bm + row) * D + kt + skoff];
      bv[r4] = *(const bf16x8*)&xnb[(size_t)(bn + row) * D + kt + skoff];
    }
    __syncthreads();
#pragma unroll
    for (int r4 = 0; r4 < 4; ++r4) {
      const int row = srow + r4 * 32;
      *(bf16x8*)&As[row][skoff] = av[r4];
      *(bf16x8*)&Bs[row][skoff] = bv[r4];
    }
    __syncthreads();
#pragma unroll
    for (int kk = 0; kk < BK; kk += 32) {
      bf16x8 af[4], bf[4];
#pragma unroll
      for (int m = 0; m < 4; ++m)
        af[m] = *(const bf16x8*)&As[wr * 64 + m * 16 + lr][kk + lk];
#pragma unroll
      for (int n = 0; n < 4; ++n)
        bf[n] = *(const bf16x8*)&Bs[wc * 64 + n * 16 + lr][kk + lk];
#pragma unroll
      for (int m = 0; m < 4; ++m)
#pragma unroll
        for (int n = 0; n < 4; ++n)
          acc[m][n] = __builtin_amdgcn_mfma_f32_16x16x32_bf16(af[m], bf[n], acc[m][n], 0, 0, 0);
    }
  }
}

// ---- 2) GEMM pass A: tile histogram into LDS, flush to global ----
__global__ __launch_bounds__(256) void gemm_hist(const unsigned short* __restrict__ xnb,
                                                 Meta* __restrict__ mt) {
  __shared__ unsigned short As[BM][LDK];
  __shared__ unsigned short Bs[BM][LDK];
  __shared__ unsigned int h[NB];
  const int tid = threadIdx.x;
  for (int i = tid; i < NB; i += 256) h[i] = 0;

  f32x4 acc[4][4] = {};
  compute_tile(xnb, As, Bs, blockIdx.x * BM, blockIdx.y * BM, tid, acc);

  __syncthreads();  // h zeroed (covered by compute_tile syncs, but be explicit)
#pragma unroll
  for (int m = 0; m < 4; ++m)
#pragma unroll
    for (int n = 0; n < 4; ++n)
#pragma unroll
      for (int e = 0; e < 4; ++e)
        atomicAdd(&h[val2bin(acc[m][n][e])], 1u);
  __syncthreads();
  for (int i = tid; i < NB; i += 256) {
    const unsigned int c = h[i];
    if (c) atomicAdd(&mt->hist[i], c);
  }
}

// ---- 3) find the two threshold bins + ranks within ----
__global__ __launch_bounds__(256) void scan_bins(Meta* __restrict__ m,
                                                 unsigned int kneg, unsigned int kpos) {
  __shared__ unsigned int part[256];
  const int tid = threadIdx.x;
  unsigned int s = 0;
  for (int i = 0; i < NB / 256; ++i) s += m->hist[tid * (NB / 256) + i];
  part[tid] = s;
  __syncthreads();
  if (tid == 0) {
    const unsigned int targets[2] = {kpos, kneg};
    unsigned int outb[2], outr[2];
    for (int t = 0; t < 2; ++t) {
      unsigned int r = targets[t], cum = 0, seg = 0;
      while (seg < 255 && cum + part[seg] <= r) { cum += part[seg]; seg++; }
      unsigned int b = seg * (NB / 256);
      while (b < NB - 1 && cum + m->hist[b] <= r) { cum += m->hist[b]; b++; }
      outb[t] = b;
      outr[t] = r - cum;
    }
    m->bp = outb[0]; m->rwp = outr[0];
    m->bn_ = outb[1]; m->rwn = outr[1];
  }
}

// ---- 4) GEMM pass B: recompute tiles (bitwise identical), strict loss +
//         boundary-bin candidate compaction ----
__global__ __launch_bounds__(256) void gemm_loss(const unsigned short* __restrict__ xnb,
                                                 Meta* __restrict__ mt,
                                                 float* __restrict__ pcand,
                                                 float* __restrict__ ncand) {
  __shared__ unsigned short As[BM][LDK];
  __shared__ unsigned short Bs[BM][LDK];
  __shared__ float lp[LCAP], ln[LCAP];
  __shared__ unsigned int lpc, lnc, pbase, nbase;
  const int tid = threadIdx.x;
  if (tid == 0) { lpc = 0; lnc = 0; }

  f32x4 acc[4][4] = {};
  compute_tile(xnb, As, Bs, blockIdx.x * BM, blockIdx.y * BM, tid, acc);

  const unsigned int bp = mt->bp, bn = mt->bn_;
  float ps = 0.f, ns = 0.f;
  unsigned int pc = 0, nc = 0;
#pragma unroll
  for (int m = 0; m < 4; ++m)
#pragma unroll
    for (int n = 0; n < 4; ++n)
#pragma unroll
      for (int e = 0; e < 4; ++e) {
        const float s = acc[m][n][e];
        const unsigned int b = (unsigned int)val2bin(s);
        if (b > bp) { pc++; ps += fmaxf(1.0f - s, 0.0f); }
        else if (b == bp) { const unsigned int i = atomicAdd(&lpc, 1u); if (i < LCAP) lp[i] = s; }
        if (b < bn) { nc++; ns += fmaxf(s, 0.0f); }
        else if (b == bn) { const unsigned int i = atomicAdd(&lnc, 1u); if (i < LCAP) ln[i] = s; }
      }
  double psd = ps, nsd = ns;
#pragma unroll
  for (int o = 32; o > 0; o >>= 1) {
    psd += __shfl_xor(psd, o);
    nsd += __shfl_xor(nsd, o);
    pc += __shfl_xor(pc, o);
    nc += __shfl_xor(nc, o);
  }
  __shared__ double sps[4], sns[4];
  __shared__ unsigned int spc[4], snc[4];
  if ((tid & 63) == 0) { const int w = tid >> 6; sps[w] = psd; sns[w] = nsd; spc[w] = pc; snc[w] = nc; }
  __syncthreads();
  if (tid == 0) {
    atomicAdd(&mt->psum, sps[0] + sps[1] + sps[2] + sps[3]);
    atomicAdd(&mt->nsum, sns[0] + sns[1] + sns[2] + sns[3]);
    atomicAdd(&mt->pcnt, spc[0] + spc[1] + spc[2] + spc[3]);
    atomicAdd(&mt->ncnt, snc[0] + snc[1] + snc[2] + snc[3]);
    pbase = atomicAdd(&mt->pcCnt, lpc < LCAP ? lpc : LCAP);
    nbase = atomicAdd(&mt->ncCnt, lnc < LCAP ? lnc : LCAP);
  }
  __syncthreads();
  const unsigned int npf = lpc < LCAP ? lpc : LCAP;
  const unsigned int nnf = lnc < LCAP ? lnc : LCAP;
  for (unsigned int i = tid; i < npf; i += 256) {
    const unsigned int gi = pbase + i;
    if (gi < CAND_CAP) pcand[gi] = lp[i];
  }
  for (unsigned int i = tid; i < nnf; i += 256) {
    const unsigned int gi = nbase + i;
    if (gi < CAND_CAP) ncand[gi] = ln[i];
  }
}

// ---- 5) exact select on candidates (key-space narrowing) + finalize ----
#define SF_T 1024
__global__ __launch_bounds__(SF_T) void select_finalize(Meta* __restrict__ m,
                                                        const float* __restrict__ pcand,
                                                        const float* __restrict__ ncand,
                                                        float* __restrict__ out) {
  __shared__ unsigned int h[1024];
  __shared__ unsigned int s_lo, s_hi, s_r;
  __shared__ unsigned int rmin[16], rmax[16], rcnt[16];
  __shared__ double racc[16];
  const int tid = threadIdx.x;
  const int lane = tid & 63, wid = tid >> 6;

  for (int side = 0; side < 2; ++side) {
    const unsigned int rawCnt = side ? m->ncCnt : m->pcCnt;
    const unsigned int cnt = rawCnt < CAND_CAP ? rawCnt : CAND_CAP;
    const float* cand = side ? ncand : pcand;
    if (tid == 0) s_r = side ? m->rwn : m->rwp;

    unsigned int kmin = 0xFFFFFFFFu, kmax = 0u;
    for (unsigned int i = tid; i < cnt; i += SF_T) {
      const unsigned int k = f2key(cand[i]);
      kmin = min(kmin, k); kmax = max(kmax, k);
    }
#pragma unroll
    for (int o = 32; o > 0; o >>= 1) {
      kmin = min(kmin, (unsigned int)__shfl_xor((int)kmin, o));
      kmax = max(kmax, (unsigned int)__shfl_xor((int)kmax, o));
    }
    if (lane == 0) { rmin[wid] = kmin; rmax[wid] = kmax; }
    __syncthreads();
    if (tid == 0) {
      unsigned int lo = 0xFFFFFFFFu, hi = 0u;
      for (int i = 0; i < SF_T / 64; ++i) { lo = min(lo, rmin[i]); hi = max(hi, rmax[i]); }
      s_lo = lo; s_hi = hi + 1u;
    }

    for (;;) {
      __syncthreads();
      const unsigned int lo = s_lo, hi = s_hi;
      if (hi - lo <= 1u) break;
      const unsigned int span = hi - lo;
      unsigned int shift = 0;
      while (((span - 1u) >> shift) > 1023u) shift++;
      for (int i = tid; i < 1024; i += SF_T) h[i] = 0;
      __syncthreads();
      for (unsigned int i = tid; i < cnt; i += SF_T) {
        const unsigned int k = f2key(cand[i]);
        if (k >= lo && k < hi) atomicAdd(&h[(k - lo) >> shift], 1u);
      }
      __syncthreads();
      if (tid == 0) {
        unsigned int r = s_r, cum = 0, d = 0;
        for (; d < 1024; ++d) { const unsigned int c = h[d]; if (cum + c > r) break; cum += c; }
        if (d == 1024) d = 1023;
        s_r = r - cum;
        const unsigned int nlo = lo + (d << shift);
        unsigned int nhi = nlo + (1u << shift);
        if (nhi > hi || nhi < nlo) nhi = hi;
        s_lo = nlo; s_hi = nhi;
      }
    }
    __syncthreads();
    const float T = key2f(s_lo);

    float accf = 0.f;
    unsigned int c2 = 0;
    for (unsigned int i = tid; i < cnt; i += SF_T) {
      const float s = cand[i];
      if (side == 0) { if (s > T) { c2++; accf += fmaxf(1.0f - s, 0.0f); } }
      else           { if (s < T) { c2++; accf += fmaxf(s, 0.0f); } }
    }
    double accd = accf;
#pragma unroll
    for (int o = 32; o > 0; o >>= 1) { accd += __shfl_xor(accd, o); c2 += __shfl_xor(c2, o); }
    if (lane == 0) { racc[wid] = accd; rcnt[wid] = c2; }
    __syncthreads();
    if (tid == 0) {
      double a = 0.0;
      unsigned int c = 0;
      for (int i = 0; i < SF_T / 64; ++i) { a += racc[i]; c += rcnt[i]; }
      if (side == 0) { m->psum += a; m->pcnt += c; }
      else           { m->nsum += a; m->ncnt += c; }
    }
    __syncthreads();
  }
  if (tid == 0)
    out[0] = (float)(m->psum / (double)m->pcnt + m->nsum / (double)m->ncnt);
}

extern "C" void kernel_launch(void* const* d_in, const int* in_sizes, int n_in,
                              void* d_out, int out_size, void* d_ws, size_t ws_size,
                              hipStream_t stream) {
  const float* x = (const float*)d_in[0];
  float* out = (float*)d_out;
  char* ws = (char*)d_ws;

  unsigned short* xnb = (unsigned short*)ws;                      // 4 MB
  float* pcand = (float*)(ws + (size_t)N * D * 2);                // 1 MB
  float* ncand = (float*)(ws + (size_t)N * D * 2 + CAND_CAP * 4); // 1 MB
  Meta* meta = (Meta*)(ws + (size_t)N * D * 2 + 2ull * CAND_CAP * 4);

  const unsigned int kneg = (unsigned int)ceil((double)NN * 0.2);          // 3355444
  const unsigned int kpos = (unsigned int)ceil((double)NN * (1.0 - 0.2));  // 13421773

  hipMemsetAsync(meta, 0, sizeof(Meta), stream);
  norm_conv<<<N, 256, 0, stream>>>(x, xnb);
  dim3 ggrid(N / BM, N / BM);
  gemm_hist<<<ggrid, 256, 0, stream>>>(xnb, meta);
  scan_bins<<<1, 256, 0, stream>>>(meta, kneg, kpos);
  gemm_loss<<<ggrid, 256, 0, stream>>>(xnb, meta, pcand, ncand);
  select_finalize<<<1, SF_T, 0, stream>>>(meta, pcand, ncand, out);
}

// Round 7
// 235.950 us; speedup vs baseline: 1.5323x; 1.2545x over previous
//
#include <hip/hip_runtime.h>
#include <hip/hip_bf16.h>
#include <math.h>

// AdaptiveContrastiveLoss: x[4096][512] f32 -> scalar f32.
// R6: R5 (parallel prefix digit-pick) + provable termination: narrowing loop
// bounded to 8 rounds, rank clamped so an owner ALWAYS exists, total==0
// collapses the range, results pre-initialized. R5 hung 600s: its owner-pick
// had no fallback if rank >= in-range count (R4 had one).
// ws: xnb 4MB | pcand 1MB | ncand 1MB | Meta ~16.5KB.

#define N 4096
#define D 512
#define NN 16777216u
#define NB 4096          // uniform value bins
#define CAND_CAP 262144  // per-side global candidate capacity (1MB)
#define LCAP 2048        // per-block LDS candidate capacity (expect ~50/block)

typedef __attribute__((ext_vector_type(8))) short bf16x8;
typedef __attribute__((ext_vector_type(4))) float f32x4;

struct Meta {
  unsigned int hist[NB];
  unsigned int bp, rwp;      // pos threshold bin + rank within bin
  unsigned int bn_, rwn;     // neg threshold bin + rank within bin
  unsigned int pcCnt, ncCnt; // candidate counts
  unsigned int pcnt, ncnt;   // strict mask counts
  double psum, nsum;         // strict mask numerators
};

// monotone value->bin: floor((s+1)*2048), clamped. identical math everywhere.
__device__ __forceinline__ int val2bin(float s) {
  int b = (int)fmaf(s, 2048.0f, 2048.0f);
  return b < 0 ? 0 : (b > NB - 1 ? NB - 1 : b);
}
__device__ __forceinline__ unsigned int f2key(float f) {
  unsigned int u = __float_as_uint(f);
  return (u & 0x80000000u) ? ~u : (u | 0x80000000u);
}
__device__ __forceinline__ float key2f(unsigned int k) {
  unsigned int u = (k & 0x80000000u) ? (k ^ 0x80000000u) : ~k;
  return __uint_as_float(u);
}
__device__ __forceinline__ unsigned short f2bf(float f) {  // RNE
  unsigned int u = __float_as_uint(f);
  u += 0x7FFFu + ((u >> 16) & 1u);
  return (unsigned short)(u >> 16);
}

// ---- 1) row norms + normalize + f32->bf16 convert ----
__global__ __launch_bounds__(256) void norm_conv(const float* __restrict__ x,
                                                 unsigned short* __restrict__ xnb) {
  const int row = blockIdx.x;
  const int tid = threadIdx.x;
  const float2 v = ((const float2*)(x + (size_t)row * D))[tid];
  float s = v.x * v.x + v.y * v.y;
#pragma unroll
  for (int o = 32; o > 0; o >>= 1) s += __shfl_xor(s, o);
  __shared__ float wsum[4];
  __shared__ float s_rinv;
  if ((tid & 63) == 0) wsum[tid >> 6] = s;
  __syncthreads();
  if (tid == 0) {
    float t = wsum[0] + wsum[1] + wsum[2] + wsum[3];
    s_rinv = 1.0f / fmaxf(sqrtf(t), 1e-8f);
  }
  __syncthreads();
  const float r = s_rinv;
  ((ushort2*)(xnb + (size_t)row * D))[tid] = make_ushort2(f2bf(v.x * r), f2bf(v.y * r));
}

// ---- shared GEMM tile core: 128x128 tile, 4 waves, acc[4][4] f32x4/lane ----
#define BM 128
#define BK 64
#define LDK 72  // padded row stride (144B: 16B-aligned, 2-way-bank free)
__device__ __forceinline__ void compute_tile(const unsigned short* __restrict__ xnb,
                                             unsigned short As[BM][LDK],
                                             unsigned short Bs[BM][LDK],
                                             int bm, int bn, int tid,
                                             f32x4 acc[4][4]) {
  const int w = tid >> 6, l = tid & 63;
  const int wr = w >> 1, wc = w & 1;
  const int lr = l & 15, lk = (l >> 4) * 8;
  const int srow = tid >> 3;        // 0..31
  const int skoff = (tid & 7) * 8;  // 0..56

  for (int kt = 0; kt < D; kt += BK) {
    bf16x8 av[4], bv[4];
#pragma unroll
    for (int r4 = 0; r4 < 4; ++r4) {
      const int row = srow + r4 * 32;
      av[r4] = *(const bf16x8*)&xnb[(size_t)(bm + row) * D + kt + skoff];
      bv[r4] = *(const bf16x8*)&xnb[(size_t)(bn + row) * D + kt + skoff];
    }
    __syncthreads();
#pragma unroll
    for (int r4 = 0; r4 < 4; ++r4) {
      const int row = srow + r4 * 32;
      *(bf16x8*)&As[row][skoff] = av[r4];
      *(bf16x8*)&Bs[row][skoff] = bv[r4];
    }
    __syncthreads();
#pragma unroll
    for (int kk = 0; kk < BK; kk += 32) {
      bf16x8 af[4], bf[4];
#pragma unroll
      for (int m = 0; m < 4; ++m)
        af[m] = *(const bf16x8*)&As[wr * 64 + m * 16 + lr][kk + lk];
#pragma unroll
      for (int n = 0; n < 4; ++n)
        bf[n] = *(const bf16x8*)&Bs[wc * 64 + n * 16 + lr][kk + lk];
#pragma unroll
      for (int m = 0; m < 4; ++m)
#pragma unroll
        for (int n = 0; n < 4; ++n)
          acc[m][n] = __builtin_amdgcn_mfma_f32_16x16x32_bf16(af[m], bf[n], acc[m][n], 0, 0, 0);
    }
  }
}

// ---- 2) GEMM pass A: tile histogram into LDS, flush to global ----
__global__ __launch_bounds__(256) void gemm_hist(const unsigned short* __restrict__ xnb,
                                                 Meta* __restrict__ mt) {
  __shared__ unsigned short As[BM][LDK];
  __shared__ unsigned short Bs[BM][LDK];
  __shared__ unsigned int h[NB];
  const int tid = threadIdx.x;
  for (int i = tid; i < NB; i += 256) h[i] = 0;

  f32x4 acc[4][4] = {};
  compute_tile(xnb, As, Bs, blockIdx.x * BM, blockIdx.y * BM, tid, acc);

  __syncthreads();
#pragma unroll
  for (int m = 0; m < 4; ++m)
#pragma unroll
    for (int n = 0; n < 4; ++n)
#pragma unroll
      for (int e = 0; e < 4; ++e)
        atomicAdd(&h[val2bin(acc[m][n][e])], 1u);
  __syncthreads();
  for (int i = tid; i < NB; i += 256) {
    const unsigned int c = h[i];
    if (c) atomicAdd(&mt->hist[i], c);
  }
}

// ---- 3) threshold bins + ranks: parallel prefix, owner-thread resolve ----
__global__ __launch_bounds__(256) void scan_bins(Meta* __restrict__ m,
                                                 unsigned int kneg, unsigned int kpos) {
  __shared__ unsigned int part[256], Q[256];
  __shared__ unsigned int res_b[2], res_r[2];
  const int tid = threadIdx.x;
  if (tid < 2) { res_b[tid] = NB - 1; res_r[tid] = 0; }  // safe defaults
  const unsigned int base = tid * (NB / 256);
  unsigned int loc[NB / 256];
  unsigned int s = 0;
#pragma unroll
  for (int i = 0; i < NB / 256; ++i) { loc[i] = m->hist[base + i]; s += loc[i]; }
  part[tid] = s;
  Q[tid] = s;
  __syncthreads();
#pragma unroll
  for (int off = 1; off < 256; off <<= 1) {
    unsigned int t = (tid >= off) ? Q[tid - off] : 0u;
    __syncthreads();
    Q[tid] += t;
    __syncthreads();
  }
  const unsigned int total = Q[255];
  const unsigned int incl = Q[tid];
  const unsigned int excl = incl - part[tid];
  const unsigned int targets[2] = {kpos, kneg};
#pragma unroll
  for (int t = 0; t < 2; ++t) {
    // clamp: owner guaranteed whenever total > 0
    const unsigned int r = (total == 0u) ? 0u
                         : (targets[t] < total ? targets[t] : total - 1u);
    if (total != 0u && excl <= r && r < incl) {  // exactly one owner thread
      unsigned int rr = r - excl, cum = 0;
      int bsel = -1;
#pragma unroll
      for (int i = 0; i < NB / 256; ++i) {
        if (bsel < 0 && cum + loc[i] > rr) bsel = i;
        else if (bsel < 0) cum += loc[i];
      }
      if (bsel < 0) bsel = NB / 256 - 1;
      res_b[t] = base + (unsigned int)bsel;
      res_r[t] = rr - cum;
    }
  }
  __syncthreads();
  if (tid == 0) {
    m->bp = res_b[0]; m->rwp = res_r[0];
    m->bn_ = res_b[1]; m->rwn = res_r[1];
  }
}

// ---- 4) GEMM pass B: recompute tiles (bitwise identical), strict loss +
//         boundary-bin candidate compaction ----
__global__ __launch_bounds__(256) void gemm_loss(const unsigned short* __restrict__ xnb,
                                                 Meta* __restrict__ mt,
                                                 float* __restrict__ pcand,
                                                 float* __restrict__ ncand) {
  __shared__ unsigned short As[BM][LDK];
  __shared__ unsigned short Bs[BM][LDK];
  __shared__ float lp[LCAP], ln[LCAP];
  __shared__ unsigned int lpc, lnc, pbase, nbase;
  const int tid = threadIdx.x;
  if (tid == 0) { lpc = 0; lnc = 0; }

  f32x4 acc[4][4] = {};
  compute_tile(xnb, As, Bs, blockIdx.x * BM, blockIdx.y * BM, tid, acc);

  const unsigned int bp = mt->bp, bn = mt->bn_;
  float ps = 0.f, ns = 0.f;
  unsigned int pc = 0, nc = 0;
#pragma unroll
  for (int m = 0; m < 4; ++m)
#pragma unroll
    for (int n = 0; n < 4; ++n)
#pragma unroll
      for (int e = 0; e < 4; ++e) {
        const float s = acc[m][n][e];
        const unsigned int b = (unsigned int)val2bin(s);
        if (b > bp) { pc++; ps += fmaxf(1.0f - s, 0.0f); }
        else if (b == bp) { const unsigned int i = atomicAdd(&lpc, 1u); if (i < LCAP) lp[i] = s; }
        if (b < bn) { nc++; ns += fmaxf(s, 0.0f); }
        else if (b == bn) { const unsigned int i = atomicAdd(&lnc, 1u); if (i < LCAP) ln[i] = s; }
      }
  double psd = ps, nsd = ns;
#pragma unroll
  for (int o = 32; o > 0; o >>= 1) {
    psd += __shfl_xor(psd, o);
    nsd += __shfl_xor(nsd, o);
    pc += __shfl_xor(pc, o);
    nc += __shfl_xor(nc, o);
  }
  __shared__ double sps[4], sns[4];
  __shared__ unsigned int spc[4], snc[4];
  if ((tid & 63) == 0) { const int w = tid >> 6; sps[w] = psd; sns[w] = nsd; spc[w] = pc; snc[w] = nc; }
  __syncthreads();
  if (tid == 0) {
    atomicAdd(&mt->psum, sps[0] + sps[1] + sps[2] + sps[3]);
    atomicAdd(&mt->nsum, sns[0] + sns[1] + sns[2] + sns[3]);
    atomicAdd(&mt->pcnt, spc[0] + spc[1] + spc[2] + spc[3]);
    atomicAdd(&mt->ncnt, snc[0] + snc[1] + snc[2] + snc[3]);
    pbase = atomicAdd(&mt->pcCnt, lpc < LCAP ? lpc : LCAP);
    nbase = atomicAdd(&mt->ncCnt, lnc < LCAP ? lnc : LCAP);
  }
  __syncthreads();
  const unsigned int npf = lpc < LCAP ? lpc : LCAP;
  const unsigned int nnf = lnc < LCAP ? lnc : LCAP;
  for (unsigned int i = tid; i < npf; i += 256) {
    const unsigned int gi = pbase + i;
    if (gi < CAND_CAP) pcand[gi] = lp[i];
  }
  for (unsigned int i = tid; i < nnf; i += 256) {
    const unsigned int gi = nbase + i;
    if (gi < CAND_CAP) ncand[gi] = ln[i];
  }
}

// ---- 5) exact select on candidates + finalize (bounded parallel pick) ----
#define SF_T 1024
__global__ __launch_bounds__(SF_T) void select_finalize(Meta* __restrict__ m,
                                                        const float* __restrict__ pcand,
                                                        const float* __restrict__ ncand,
                                                        float* __restrict__ out) {
  __shared__ unsigned int h[1024], P[1024];
  __shared__ unsigned int s_lo, s_hi, s_r;
  __shared__ unsigned int rmin[16], rmax[16], rcnt[16];
  __shared__ double racc[16];
  const int tid = threadIdx.x;
  const int lane = tid & 63, wid = tid >> 6;

  for (int side = 0; side < 2; ++side) {
    const unsigned int rawCnt = side ? m->ncCnt : m->pcCnt;
    const unsigned int cnt = rawCnt < CAND_CAP ? rawCnt : CAND_CAP;
    const float* cand = side ? ncand : pcand;
    if (tid == 0) s_r = side ? m->rwn : m->rwp;

    // key min/max over candidates
    unsigned int kmin = 0xFFFFFFFFu, kmax = 0u;
    for (unsigned int i = tid; i < cnt; i += SF_T) {
      const unsigned int k = f2key(cand[i]);
      kmin = min(kmin, k); kmax = max(kmax, k);
    }
#pragma unroll
    for (int o = 32; o > 0; o >>= 1) {
      kmin = min(kmin, (unsigned int)__shfl_xor((int)kmin, o));
      kmax = max(kmax, (unsigned int)__shfl_xor((int)kmax, o));
    }
    if (lane == 0) { rmin[wid] = kmin; rmax[wid] = kmax; }
    __syncthreads();
    if (tid == 0) {
      unsigned int lo = 0xFFFFFFFFu, hi = 0u;
      for (int i = 0; i < SF_T / 64; ++i) { lo = min(lo, rmin[i]); hi = max(hi, rmax[i]); }
      if (hi < lo) { lo = 0u; hi = 0u; }  // cnt==0 edge: degenerate range
      s_lo = lo; s_hi = hi + 1u;
    }

    // narrow [lo,hi) by 1024-way histogram. Bounded: span shrinks >=1024x
    // per round (4 rounds max for 2^32); 8 is a hard safety bound.
    for (int round = 0; round < 8; ++round) {
      __syncthreads();
      const unsigned int lo = s_lo, hi = s_hi;
      const unsigned int r = s_r;
      if (hi - lo <= 1u) break;
      const unsigned int span = hi - lo;
      unsigned int shift = 0;
      while (((span - 1u) >> shift) > 1023u) shift++;
      h[tid] = 0;
      __syncthreads();
      for (unsigned int i = tid; i < cnt; i += SF_T) {
        const unsigned int k = f2key(cand[i]);
        if (k >= lo && k < hi) atomicAdd(&h[(k - lo) >> shift], 1u);
      }
      __syncthreads();
      // parallel inclusive prefix over h -> P (Hillis-Steele, 10 steps)
      const unsigned int myh = h[tid];
      P[tid] = myh;
      __syncthreads();
#pragma unroll
      for (int off = 1; off < 1024; off <<= 1) {
        const unsigned int t = (tid >= off) ? P[tid - off] : 0u;
        __syncthreads();
        P[tid] += t;
        __syncthreads();
      }
      const unsigned int total = P[SF_T - 1];
      if (total == 0u) {               // no keys in range: collapse & exit
        if (tid == 0) s_hi = s_lo + 1u;
        continue;                       // next round breaks
      }
      const unsigned int rr = r < total ? r : total - 1u;  // owner guaranteed
      const unsigned int incl = P[tid];
      const unsigned int excl = incl - myh;
      if (excl <= rr && rr < incl) {   // exactly one owner (myh>0 there)
        s_r = rr - excl;
        const unsigned int nlo = lo + ((unsigned int)tid << shift);
        unsigned int nhi = nlo + (1u << shift);
        if (nhi > hi || nhi < nlo) nhi = hi;
        s_lo = nlo; s_hi = nhi;
      }
    }
    __syncthreads();
    const float T = key2f(s_lo);

    // strict boundary contributions
    float accf = 0.f;
    unsigned int c2 = 0;
    for (unsigned int i = tid; i < cnt; i += SF_T) {
      const float s = cand[i];
      if (side == 0) { if (s > T) { c2++; accf += fmaxf(1.0f - s, 0.0f); } }
      else           { if (s < T) { c2++; accf += fmaxf(s, 0.0f); } }
    }
    double accd = accf;
#pragma unroll
    for (int o = 32; o > 0; o >>= 1) { accd += __shfl_xor(accd, o); c2 += __shfl_xor(c2, o); }
    if (lane == 0) { racc[wid] = accd; rcnt[wid] = c2; }
    __syncthreads();
    if (tid == 0) {
      double a = 0.0;
      unsigned int c = 0;
      for (int i = 0; i < SF_T / 64; ++i) { a += racc[i]; c += rcnt[i]; }
      if (side == 0) { m->psum += a; m->pcnt += c; }
      else           { m->nsum += a; m->ncnt += c; }
    }
    __syncthreads();
  }
  if (tid == 0)
    out[0] = (float)(m->psum / (double)m->pcnt + m->nsum / (double)m->ncnt);
}

extern "C" void kernel_launch(void* const* d_in, const int* in_sizes, int n_in,
                              void* d_out, int out_size, void* d_ws, size_t ws_size,
                              hipStream_t stream) {
  const float* x = (const float*)d_in[0];
  float* out = (float*)d_out;
  char* ws = (char*)d_ws;

  unsigned short* xnb = (unsigned short*)ws;                      // 4 MB
  float* pcand = (float*)(ws + (size_t)N * D * 2);                // 1 MB
  float* ncand = (float*)(ws + (size_t)N * D * 2 + CAND_CAP * 4); // 1 MB
  Meta* meta = (Meta*)(ws + (size_t)N * D * 2 + 2ull * CAND_CAP * 4);

  const unsigned int kneg = (unsigned int)ceil((double)NN * 0.2);          // 3355444
  const unsigned int kpos = (unsigned int)ceil((double)NN * (1.0 - 0.2));  // 13421773

  hipMemsetAsync(meta, 0, sizeof(Meta), stream);
  norm_conv<<<N, 256, 0, stream>>>(x, xnb);
  dim3 ggrid(N / BM, N / BM);
  gemm_hist<<<ggrid, 256, 0, stream>>>(xnb, meta);
  scan_bins<<<1, 256, 0, stream>>>(meta, kneg, kpos);
  gemm_loss<<<ggrid, 256, 0, stream>>>(xnb, meta, pcand, ncand);
  select_finalize<<<1, SF_T, 0, stream>>>(meta, pcand, ncand, out);
}